// Round 4
// baseline (508.530 us; speedup 1.0000x reference)
//
#include <hip/hip_runtime.h>
#include <hip/hip_bf16.h>

#define NB 8192
#define NE 100000

typedef __bf16 bf16x8 __attribute__((ext_vector_type(8)));
typedef __bf16 bf16x4 __attribute__((ext_vector_type(4)));
typedef float  f32x4  __attribute__((ext_vector_type(4)));

// ---- cross-lane reductions ------------------------------------------------
template<int C>
__device__ __forceinline__ float dpp_mov(float v) {
  return __int_as_float(__builtin_amdgcn_update_dpp(
      0, __float_as_int(v), C, 0xF, 0xF, true));
}

// sum across each 16-lane group (DPP only, VALU pipe, no lgkm waits)
__device__ __forceinline__ float red16(float v) {
  v += dpp_mov<0xB1>(v);   // xor 1 (quad_perm)
  v += dpp_mov<0x4E>(v);   // xor 2 (quad_perm)
  v += dpp_mov<0x141>(v);  // row_half_mirror -> sum over 8
  v += dpp_mov<0x140>(v);  // row_mirror      -> sum over 16
  return v;
}

// overflow-free tanh: (1-e)/(1+e), e = exp(-2|x|) in (0,1]
__device__ __forceinline__ float fast_tanh(float x) {
  float e = __expf(-2.0f * fabsf(x));
  float t = (1.0f - e) * __builtin_amdgcn_rcpf(1.0f + e);
  return copysignf(t, x);
}

// ---- prep: pack W2 (= att_w rows 64..127) into MFMA B-fragment layout, and
// precompute qpart[rid][j] = sum_k qrel[rid][k] * att_w[k][j] for all 1000 rids.
__global__ void prep_kernel(const float* __restrict__ att_w,
                            const float* __restrict__ qrel,
                            __bf16* __restrict__ wsf,      // 8*2*64*8 bf16 = 16 KB
                            float*  __restrict__ qpart) {  // 1000*128 f32
  const int t = threadIdx.x;      // 128 threads
  const int bid = blockIdx.x;
  if (bid == 0) {
    // B frag (tc,ks): lane l, elem e -> W2[k][j], k = ks*32 + (l>>4)*8 + e,
    // j = tc*16 + (l&15); W2[k][j] = att_w[(64+k)*128 + j]
    for (int i = t; i < 8192; i += 128) {
      int e  = i & 7;
      int l  = (i >> 3) & 63;
      int ks = (i >> 9) & 1;
      int tc = i >> 10;
      int k = ks * 32 + ((l >> 4) << 3) + e;
      int j = tc * 16 + (l & 15);
      wsf[i] = (__bf16)att_w[(64 + k) * 128 + j];
    }
  } else {
    int rid = bid - 1;            // 0..999
    float acc = 0.f;
    for (int k = 0; k < 64; ++k)
      acc += qrel[rid * 64 + k] * att_w[k * 128 + t];
    qpart[rid * 128 + t] = acc;
  }
}

// ---- main: one block per batch row b ------------------------------------
__global__ __launch_bounds__(256, 6)
void attn_kernel(const float* __restrict__ inp,
                 const int*   __restrict__ nb,
                 const int*   __restrict__ qid_p,
                 const float* __restrict__ wgt,
                 const float* __restrict__ mlp,
                 const float* __restrict__ attv,
                 const __bf16* __restrict__ wsf,
                 const float* __restrict__ qpart_t,
                 float* __restrict__ out) {
  __shared__ __attribute__((aligned(16))) __bf16 T16[128][72];  // transformed (bf16)
  __shared__ float qp[128], plog[128], awl[128], wrat[128];
  __shared__ float part[4][64];

  const int t    = threadIdx.x;
  const int lane = t & 63;
  const int w    = t >> 6;       // wave id 0..3
  const int g    = lane >> 4;    // 16-lane group 0..3
  const int q    = lane & 15;
  const int b    = blockIdx.x;

  if (t < 128) {
    int qid = qid_p[b];
    qp[t] = qpart_t[qid * 128 + t];
    float2 w01 = reinterpret_cast<const float2*>(wgt)[(size_t)b * 128 + t];
    wrat[t] = w01.x / (w01.y + 1.0f);
  }

  // ---- phase A: projection. group of 16 lanes = one row, lane = 4 dims ----
  {
    // prefetch all neighbor ids first: makes every gather independent
    int2 re[8];
#pragma unroll
    for (int i = 0; i < 8; ++i) {
      int n = w * 32 + i * 4 + g;
      re[i] = *reinterpret_cast<const int2*>(&nb[((size_t)b * 128 + n) * 2]);
    }
#pragma unroll
    for (int i = 0; i < 8; ++i) {
      int n = w * 32 + i * 4 + g;
      f32x4 iv = *reinterpret_cast<const f32x4*>(&inp[((size_t)b * 128 + n) * 64 + q * 4]);
      f32x4 rv = *reinterpret_cast<const f32x4*>(&mlp[(size_t)re[i].x * 64 + q * 4]);
      float s1 = red16(rv[0]*rv[0] + rv[1]*rv[1] + rv[2]*rv[2] + rv[3]*rv[3]); // ||r||^2
      float s2 = red16(iv[0]*rv[0] + iv[1]*rv[1] + iv[2]*rv[2] + iv[3]*rv[3]); // in.r
      float f  = s2 / fmaxf(s1, 1e-24f);
      float m  = (re[i].y >= NE) ? 0.0f : 1.0f;
      bf16x4 tv;
#pragma unroll
      for (int j = 0; j < 4; ++j) tv[j] = (__bf16)((iv[j] - f * rv[j]) * m);
      *reinterpret_cast<bf16x4*>(&T16[n][q * 4]) = tv;
    }
  }
  __syncthreads();   // T16 (cross-wave use in phase C), qp, wrat

  // ---- phase B: C = T @ W2 (+qpart), per wave rows [32w, 32w+32) ----
  float vv[8];
#pragma unroll
  for (int tc = 0; tc < 8; ++tc) vv[tc] = attv[tc * 16 + q];

  f32x4 acc[2][8];
#pragma unroll
  for (int tc = 0; tc < 8; ++tc) {
    float qv = qp[tc * 16 + q];       // D layout: col = lane&15 (all 4 regs)
    acc[0][tc] = f32x4{qv, qv, qv, qv};
    acc[1][tc] = f32x4{qv, qv, qv, qv};
  }
  bf16x8 af[2][2];
#pragma unroll
  for (int tr = 0; tr < 2; ++tr) {
    int row = w * 32 + tr * 16 + q;   // A layout: row = lane&15, k = (lane>>4)*8 + e
    af[tr][0] = *reinterpret_cast<const bf16x8*>(&T16[row][g * 8]);
    af[tr][1] = *reinterpret_cast<const bf16x8*>(&T16[row][g * 8 + 32]);
  }
#pragma unroll
  for (int tc = 0; tc < 8; ++tc) {
    // B-frags streamed from L2 (keeps only 8 VGPRs live instead of 64)
    bf16x8 b0 = *reinterpret_cast<const bf16x8*>(wsf + ((tc * 2 + 0) * 64 + lane) * 8);
    bf16x8 b1 = *reinterpret_cast<const bf16x8*>(wsf + ((tc * 2 + 1) * 64 + lane) * 8);
    acc[0][tc] = __builtin_amdgcn_mfma_f32_16x16x32_bf16(af[0][0], b0, acc[0][tc], 0, 0, 0);
    acc[1][tc] = __builtin_amdgcn_mfma_f32_16x16x32_bf16(af[1][0], b0, acc[1][tc], 0, 0, 0);
    acc[0][tc] = __builtin_amdgcn_mfma_f32_16x16x32_bf16(af[0][1], b1, acc[0][tc], 0, 0, 0);
    acc[1][tc] = __builtin_amdgcn_mfma_f32_16x16x32_bf16(af[1][1], b1, acc[1][tc], 0, 0, 0);
  }

  // ---- epilogue: logit_n = sum_j tanh(C[n][j]) * v[j] ----
#pragma unroll
  for (int tr = 0; tr < 2; ++tr) {
    float p0 = 0.f, p1 = 0.f, p2 = 0.f, p3 = 0.f;
#pragma unroll
    for (int tc = 0; tc < 8; ++tc) {
      p0 += fast_tanh(acc[tr][tc][0]) * vv[tc];
      p1 += fast_tanh(acc[tr][tc][1]) * vv[tc];
      p2 += fast_tanh(acc[tr][tc][2]) * vv[tc];
      p3 += fast_tanh(acc[tr][tc][3]) * vv[tc];
    }
    p0 = red16(p0); p1 = red16(p1); p2 = red16(p2); p3 = red16(p3);
    if (q == 0) {
      int row = w * 32 + tr * 16 + g * 4;  // D layout: row = (lane>>4)*4 + reg
      plog[row + 0] = p0;
      plog[row + 1] = p1;
      plog[row + 2] = p2;
      plog[row + 3] = p3;
    }
  }
  __syncthreads();

  // ---- softmax over n (wave 0), + weight ratio, write attention_weight ----
  if (w == 0) {
    // re-derive mask from neighbor entity id (no mlog LDS array)
    int e0i = nb[((size_t)b * 128 + lane) * 2 + 1];
    int e1i = nb[((size_t)b * 128 + lane + 64) * 2 + 1];
    float l0 = plog[lane]      - ((e0i == NE) ? 1e19f : 0.0f);
    float l1 = plog[lane + 64] - ((e1i == NE) ? 1e19f : 0.0f);
    float m = fmaxf(l0, l1);
    m = fmaxf(m, __shfl_xor(m, 1, 64));
    m = fmaxf(m, __shfl_xor(m, 2, 64));
    m = fmaxf(m, __shfl_xor(m, 4, 64));
    m = fmaxf(m, __shfl_xor(m, 8, 64));
    m = fmaxf(m, __shfl_xor(m, 16, 64));
    m = fmaxf(m, __shfl_xor(m, 32, 64));
    float e0 = __expf(l0 - m), e1 = __expf(l1 - m);
    float s = e0 + e1;
    s += __shfl_xor(s, 1, 64);
    s += __shfl_xor(s, 2, 64);
    s += __shfl_xor(s, 4, 64);
    s += __shfl_xor(s, 8, 64);
    s += __shfl_xor(s, 16, 64);
    s += __shfl_xor(s, 32, 64);
    float inv = 1.0f / s;
    float a0 = e0 * inv + wrat[lane];
    float a1 = e1 * inv + wrat[lane + 64];
    awl[lane] = a0; awl[lane + 64] = a1;
    float* awout = out + (size_t)NB * 64;          // second output, flat-concat
    awout[(size_t)b * 128 + lane]      = a0;
    awout[(size_t)b * 128 + lane + 64] = a1;
  }
  __syncthreads();

  // ---- phase C: output[d] = sum_n T[n][d] * aw[n] ----
  {
    float s = 0.f;
#pragma unroll 8
    for (int i = 0; i < 32; ++i) {
      int n = w * 32 + i;
      s += (float)T16[n][lane] * awl[n];
    }
    part[w][lane] = s;
  }
  __syncthreads();
  if (t < 64)
    out[(size_t)b * 64 + t] = part[0][t] + part[1][t] + part[2][t] + part[3][t];
}

// ---- host ----------------------------------------------------------------
extern "C" void kernel_launch(void* const* d_in, const int* in_sizes, int n_in,
                              void* d_out, int out_size, void* d_ws, size_t ws_size,
                              hipStream_t stream) {
  const float* inp  = (const float*)d_in[0];
  const int*   nb   = (const int*)d_in[1];
  const int*   qid  = (const int*)d_in[2];
  const float* wgt  = (const float*)d_in[3];
  const float* mlp  = (const float*)d_in[4];
  const float* qrel = (const float*)d_in[5];
  const float* attw = (const float*)d_in[6];
  const float* attv = (const float*)d_in[7];
  float* out = (float*)d_out;

  // ws layout: [0,16384) bf16 B-fragments; [16384, 16384+512000) qpart f32
  __bf16* wsf   = (__bf16*)d_ws;
  float*  qpart = (float*)((char*)d_ws + 16384);

  prep_kernel<<<1001, 128, 0, stream>>>(attw, qrel, wsf, qpart);
  attn_kernel<<<NB, 256, 0, stream>>>(inp, nb, qid, wgt, mlp, attv, wsf, qpart, out);
}

// Round 5
// 475.736 us; speedup vs baseline: 1.0689x; 1.0689x over previous
//
#include <hip/hip_runtime.h>
#include <hip/hip_bf16.h>

#define NB 8192
#define NE 100000

typedef __bf16 bf16x8 __attribute__((ext_vector_type(8)));
typedef __bf16 bf16x4 __attribute__((ext_vector_type(4)));
typedef float  f32x4  __attribute__((ext_vector_type(4)));

// ---- cross-lane helpers ---------------------------------------------------
template<int C>
__device__ __forceinline__ float dpp_mov(float v) {
  return __int_as_float(__builtin_amdgcn_update_dpp(
      0, __float_as_int(v), C, 0xF, 0xF, true));
}

// sum across each 16-lane group (DPP only, VALU pipe, no lgkm waits)
__device__ __forceinline__ float red16(float v) {
  v += dpp_mov<0xB1>(v);   // xor 1 (quad_perm)
  v += dpp_mov<0x4E>(v);   // xor 2 (quad_perm)
  v += dpp_mov<0x141>(v);  // row_half_mirror -> sum over 8
  v += dpp_mov<0x140>(v);  // row_mirror      -> sum over 16
  return v;
}

__device__ __forceinline__ float swz_xor16(float v) {
  return __int_as_float(__builtin_amdgcn_ds_swizzle(__float_as_int(v), 0x401F));
}

// overflow-free tanh: (1-e)/(1+e), e = exp(-2|x|) in (0,1]
__device__ __forceinline__ float fast_tanh(float x) {
  float e = __expf(-2.0f * fabsf(x));
  float t = (1.0f - e) * __builtin_amdgcn_rcpf(1.0f + e);
  return copysignf(t, x);
}

// ---- prep: pack W2 (= att_w rows 64..127) into MFMA B-fragment layout, and
// precompute qpart[rid][j] = sum_k qrel[rid][k] * att_w[k][j] for all 1000 rids.
__global__ void prep_kernel(const float* __restrict__ att_w,
                            const float* __restrict__ qrel,
                            __bf16* __restrict__ wsf,      // 8*2*64*8 bf16 = 16 KB
                            float*  __restrict__ qpart) {  // 1000*128 f32
  const int t = threadIdx.x;      // 128 threads
  const int bid = blockIdx.x;
  if (bid == 0) {
    for (int i = t; i < 8192; i += 128) {
      int e  = i & 7;
      int l  = (i >> 3) & 63;
      int ks = (i >> 9) & 1;
      int tc = i >> 10;
      int k = ks * 32 + ((l >> 4) << 3) + e;
      int j = tc * 16 + (l & 15);
      wsf[i] = (__bf16)att_w[(64 + k) * 128 + j];
    }
  } else {
    int rid = bid - 1;            // 0..999
    float acc = 0.f;
    for (int k = 0; k < 64; ++k)
      acc += qrel[rid * 64 + k] * att_w[k * 128 + t];
    qpart[rid * 128 + t] = acc;
  }
}

// ---- main: one block per batch row b; waves barrier only twice -----------
__global__ __launch_bounds__(256, 4)
void attn_kernel(const float* __restrict__ inp,
                 const int*   __restrict__ nb,
                 const int*   __restrict__ qid_p,
                 const float* __restrict__ wgt,
                 const float* __restrict__ mlp,
                 const float* __restrict__ attv,
                 const __bf16* __restrict__ wsf,
                 const float* __restrict__ qpart_t,
                 float* __restrict__ out) {
  __shared__ __attribute__((aligned(16))) __bf16 T16[128][72];  // transformed (bf16)
  __shared__ float plog[128], mlog[128], awl[128];
  __shared__ float part[4][64];

  const int t    = threadIdx.x;
  const int lane = t & 63;
  const int w    = t >> 6;       // wave id 0..3
  const int g    = lane >> 4;    // 16-lane group 0..3
  const int q    = lane & 15;
  const int b    = blockIdx.x;

  // ---- wave-local preloads (no LDS, no cross-wave dependency) ----
  const int qid = qid_p[b];                        // uniform -> s_load
  float qpv[8], vv[8];
#pragma unroll
  for (int tc = 0; tc < 8; ++tc) {
    qpv[tc] = qpart_t[qid * 128 + tc * 16 + q];    // L2-hot 512KB table
    vv[tc]  = attv[tc * 16 + q];
  }
  const int rown = w * 32 + (lane & 31);           // this lane's softmax row
  float2 w01 = reinterpret_cast<const float2*>(wgt)[(size_t)b * 128 + rown];
  const float wr = w01.x / (w01.y + 1.0f);

  // ---- phase A: projection. 16-lane group = one row, lane = 4 dims ----
  {
    int2 re[8];
#pragma unroll
    for (int i = 0; i < 8; ++i) {
      int n = w * 32 + i * 4 + g;
      re[i] = *reinterpret_cast<const int2*>(&nb[((size_t)b * 128 + n) * 2]);
    }
#pragma unroll
    for (int i = 0; i < 8; ++i) {
      int n = w * 32 + i * 4 + g;
      f32x4 iv = *reinterpret_cast<const f32x4*>(&inp[((size_t)b * 128 + n) * 64 + q * 4]);
      f32x4 rv = *reinterpret_cast<const f32x4*>(&mlp[(size_t)re[i].x * 64 + q * 4]);
      float s1 = red16(rv[0]*rv[0] + rv[1]*rv[1] + rv[2]*rv[2] + rv[3]*rv[3]); // ||r||^2
      float s2 = red16(iv[0]*rv[0] + iv[1]*rv[1] + iv[2]*rv[2] + iv[3]*rv[3]); // in.r
      float f  = s2 / fmaxf(s1, 1e-24f);
      float m  = (re[i].y >= NE) ? 0.0f : 1.0f;
      bf16x4 tv;
#pragma unroll
      for (int j = 0; j < 4; ++j) tv[j] = (__bf16)((iv[j] - f * rv[j]) * m);
      *reinterpret_cast<bf16x4*>(&T16[n][q * 4]) = tv;
      if (q == 0) mlog[n] = (re[i].y == NE) ? 1e19f : 0.0f;
    }
  }
  // in-wave fence: phase B reads only THIS wave's T16 rows -> no __syncthreads
  asm volatile("s_waitcnt lgkmcnt(0)" ::: "memory");

  // ---- phase B: C = T @ W2 (+qpart) for own 32 rows; logits via tanh ----
  bf16x8 af[2][2];
#pragma unroll
  for (int tr = 0; tr < 2; ++tr) {
    int row = w * 32 + tr * 16 + q;   // A layout: row = lane&15, k = (lane>>4)*8 + e
    af[tr][0] = *reinterpret_cast<const bf16x8*>(&T16[row][g * 8]);
    af[tr][1] = *reinterpret_cast<const bf16x8*>(&T16[row][g * 8 + 32]);
  }
  float p[2][4] = {{0,0,0,0},{0,0,0,0}};
#pragma unroll
  for (int h = 0; h < 2; ++h) {       // two tc-halves: halves acc VGPR pressure
    f32x4 acc[2][4];
#pragma unroll
    for (int tc2 = 0; tc2 < 4; ++tc2) {
      float qv = qpv[h * 4 + tc2];    // D layout: col = lane&15 (all 4 regs)
      acc[0][tc2] = f32x4{qv, qv, qv, qv};
      acc[1][tc2] = f32x4{qv, qv, qv, qv};
    }
#pragma unroll
    for (int tc2 = 0; tc2 < 4; ++tc2) {
      int tc = h * 4 + tc2;
      bf16x8 b0 = *reinterpret_cast<const bf16x8*>(wsf + ((tc * 2 + 0) * 64 + lane) * 8);
      bf16x8 b1 = *reinterpret_cast<const bf16x8*>(wsf + ((tc * 2 + 1) * 64 + lane) * 8);
      acc[0][tc2] = __builtin_amdgcn_mfma_f32_16x16x32_bf16(af[0][0], b0, acc[0][tc2], 0, 0, 0);
      acc[1][tc2] = __builtin_amdgcn_mfma_f32_16x16x32_bf16(af[1][0], b0, acc[1][tc2], 0, 0, 0);
      acc[0][tc2] = __builtin_amdgcn_mfma_f32_16x16x32_bf16(af[0][1], b1, acc[0][tc2], 0, 0, 0);
      acc[1][tc2] = __builtin_amdgcn_mfma_f32_16x16x32_bf16(af[1][1], b1, acc[1][tc2], 0, 0, 0);
    }
#pragma unroll
    for (int tr = 0; tr < 2; ++tr)
#pragma unroll
      for (int tc2 = 0; tc2 < 4; ++tc2) {
        float v = vv[h * 4 + tc2];
        p[tr][0] += fast_tanh(acc[tr][tc2][0]) * v;
        p[tr][1] += fast_tanh(acc[tr][tc2][1]) * v;
        p[tr][2] += fast_tanh(acc[tr][tc2][2]) * v;
        p[tr][3] += fast_tanh(acc[tr][tc2][3]) * v;
      }
  }
#pragma unroll
  for (int tr = 0; tr < 2; ++tr) {
    float p0 = red16(p[tr][0]), p1 = red16(p[tr][1]);
    float p2 = red16(p[tr][2]), p3 = red16(p[tr][3]);
    if (q == 0) {
      int row = w * 32 + tr * 16 + g * 4;  // D layout: row = (lane>>4)*4 + reg
      plog[row + 0] = p0;
      plog[row + 1] = p1;
      plog[row + 2] = p2;
      plog[row + 3] = p3;
    }
  }
  __syncthreads();   // barrier 1 of 2: plog/mlog complete (softmax needs all rows)

  // ---- softmax: every wave computes m,s redundantly; aw for own rows ----
  {
    float l0 = plog[lane]      - mlog[lane];
    float l1 = plog[lane + 64] - mlog[lane + 64];
    float m = fmaxf(l0, l1);
    m = fmaxf(m, __shfl_xor(m, 1, 64));
    m = fmaxf(m, __shfl_xor(m, 2, 64));
    m = fmaxf(m, __shfl_xor(m, 4, 64));
    m = fmaxf(m, __shfl_xor(m, 8, 64));
    m = fmaxf(m, __shfl_xor(m, 16, 64));
    m = fmaxf(m, __shfl_xor(m, 32, 64));
    float e0 = __expf(l0 - m), e1 = __expf(l1 - m);
    float s = e0 + e1;
    s += __shfl_xor(s, 1, 64);
    s += __shfl_xor(s, 2, 64);
    s += __shfl_xor(s, 4, 64);
    s += __shfl_xor(s, 8, 64);
    s += __shfl_xor(s, 16, 64);
    s += __shfl_xor(s, 32, 64);
    float inv = __builtin_amdgcn_rcpf(s) * (2.0f - s * __builtin_amdgcn_rcpf(s)); // NR-refined 1/s
    float lg = plog[rown] - mlog[rown];
    float aw = __expf(lg - m) * inv + wr;
    if (lane < 32) {
      awl[rown] = aw;
      float* awout = out + (size_t)NB * 64;
      awout[(size_t)b * 128 + rown] = aw;    // coalesced per-wave slice
    }
  }
  asm volatile("s_waitcnt lgkmcnt(0)" ::: "memory");  // awl in-wave RAW

  // ---- phase C: own-rows partial of output[d] = sum_n T[n][d]*aw[n] ----
  {
    f32x4 s4 = {0.f, 0.f, 0.f, 0.f};
#pragma unroll
    for (int i = 0; i < 8; ++i) {
      int n = w * 32 + i * 4 + g;
      bf16x4 tv = *reinterpret_cast<const bf16x4*>(&T16[n][q * 4]);
      float a = awl[n];
      s4[0] += (float)tv[0] * a;
      s4[1] += (float)tv[1] * a;
      s4[2] += (float)tv[2] * a;
      s4[3] += (float)tv[3] * a;
    }
#pragma unroll
    for (int c = 0; c < 4; ++c) {        // reduce across the 4 row-groups
      float v = s4[c];
      v += swz_xor16(v);
      v += __shfl_xor(v, 32, 64);
      s4[c] = v;
    }
    if (lane < 16) *reinterpret_cast<f32x4*>(&part[w][lane * 4]) = s4;
  }
  __syncthreads();   // barrier 2 of 2: part complete
  if (t < 64)
    out[(size_t)b * 64 + t] = part[0][t] + part[1][t] + part[2][t] + part[3][t];
}

// ---- host ----------------------------------------------------------------
extern "C" void kernel_launch(void* const* d_in, const int* in_sizes, int n_in,
                              void* d_out, int out_size, void* d_ws, size_t ws_size,
                              hipStream_t stream) {
  const float* inp  = (const float*)d_in[0];
  const int*   nb   = (const int*)d_in[1];
  const int*   qid  = (const int*)d_in[2];
  const float* wgt  = (const float*)d_in[3];
  const float* mlp  = (const float*)d_in[4];
  const float* qrel = (const float*)d_in[5];
  const float* attw = (const float*)d_in[6];
  const float* attv = (const float*)d_in[7];
  float* out = (float*)d_out;

  // ws layout: [0,16384) bf16 B-fragments; [16384, 16384+512000) qpart f32
  __bf16* wsf   = (__bf16*)d_ws;
  float*  qpart = (float*)((char*)d_ws + 16384);

  prep_kernel<<<1001, 128, 0, stream>>>(attw, qrel, wsf, qpart);
  attn_kernel<<<NB, 256, 0, stream>>>(inp, nb, qid, wgt, mlp, attv, wsf, qpart, out);
}

// Round 6
// 458.744 us; speedup vs baseline: 1.1085x; 1.0370x over previous
//
#include <hip/hip_runtime.h>
#include <hip/hip_bf16.h>

#define NB 8192
#define NE 100000

typedef __bf16 bf16x8 __attribute__((ext_vector_type(8)));
typedef __bf16 bf16x4 __attribute__((ext_vector_type(4)));
typedef float  f32x4  __attribute__((ext_vector_type(4)));

// ---- cross-lane helpers ---------------------------------------------------
template<int C>
__device__ __forceinline__ float dpp_mov(float v) {
  return __int_as_float(__builtin_amdgcn_update_dpp(
      0, __float_as_int(v), C, 0xF, 0xF, true));
}

// sum across each 16-lane group (DPP only, VALU pipe, no lgkm waits)
__device__ __forceinline__ float red16(float v) {
  v += dpp_mov<0xB1>(v);   // xor 1 (quad_perm)
  v += dpp_mov<0x4E>(v);   // xor 2 (quad_perm)
  v += dpp_mov<0x141>(v);  // row_half_mirror -> sum over 8
  v += dpp_mov<0x140>(v);  // row_mirror      -> sum over 16
  return v;
}

__device__ __forceinline__ float swz_xor16(float v) {
  return __int_as_float(__builtin_amdgcn_ds_swizzle(__float_as_int(v), 0x401F));
}

// overflow-free tanh: (1-e)/(1+e), e = exp(-2|x|) in (0,1]
__device__ __forceinline__ float fast_tanh(float x) {
  float e = __expf(-2.0f * fabsf(x));
  float t = (1.0f - e) * __builtin_amdgcn_rcpf(1.0f + e);
  return copysignf(t, x);
}

// ---- prep: pack W2 (= att_w rows 64..127) into MFMA B-fragment layout, and
// precompute qpart[rid][j] = sum_k qrel[rid][k] * att_w[k][j] for all 1000 rids.
__global__ void prep_kernel(const float* __restrict__ att_w,
                            const float* __restrict__ qrel,
                            __bf16* __restrict__ wsf,      // 8*2*64*8 bf16 = 16 KB
                            float*  __restrict__ qpart) {  // 1000*128 f32
  const int t = threadIdx.x;      // 128 threads
  const int bid = blockIdx.x;
  if (bid == 0) {
    for (int i = t; i < 8192; i += 128) {
      int e  = i & 7;
      int l  = (i >> 3) & 63;
      int ks = (i >> 9) & 1;
      int tc = i >> 10;
      int k = ks * 32 + ((l >> 4) << 3) + e;
      int j = tc * 16 + (l & 15);
      wsf[i] = (__bf16)att_w[(64 + k) * 128 + j];
    }
  } else {
    int rid = bid - 1;            // 0..999
    float acc = 0.f;
    for (int k = 0; k < 64; ++k)
      acc += qrel[rid * 64 + k] * att_w[k * 128 + t];
    qpart[rid * 128 + t] = acc;
  }
}

// ---- main: one block per batch row b; T lives in MFMA-fragment registers --
__global__ __launch_bounds__(256, 4)
void attn_kernel(const float* __restrict__ inp,
                 const int*   __restrict__ nb,
                 const int*   __restrict__ qid_p,
                 const float* __restrict__ wgt,
                 const float* __restrict__ mlp,
                 const float* __restrict__ attv,
                 const __bf16* __restrict__ wsf,
                 const float* __restrict__ qpart_t,
                 float* __restrict__ out) {
  __shared__ float plog[128], awl[128];
  __shared__ float part[4][64];

  const int t    = threadIdx.x;
  const int lane = t & 63;
  const int w    = t >> 6;       // wave id 0..3
  const int r    = lane & 15;    // fragment row
  const int c    = lane >> 4;    // fragment k-chunk 0..3
  const int b    = blockIdx.x;

  // ---- wave-local preloads (no cross-wave dependency) ----
  const int qid = qid_p[b];                        // uniform -> s_load
  float qpv[8], vv[8];
#pragma unroll
  for (int tc = 0; tc < 8; ++tc) {
    qpv[tc] = qpart_t[qid * 128 + tc * 16 + r];    // L2-hot 512KB table
    vv[tc]  = attv[tc * 16 + r];
  }
  const int rown = w * 32 + (lane & 31);           // this lane's softmax row
  float2 w01 = reinterpret_cast<const float2*>(wgt)[(size_t)b * 128 + rown];
  const float wr = w01.x / (w01.y + 1.0f);

  // ---- phase A: projection directly in A-fragment layout ----
  // af[tr][ks] elem e  <->  T[w*32 + tr*16 + r][ks*32 + c*8 + e]
  bf16x8 af[2][2];
  int2 re[2];
#pragma unroll
  for (int tr = 0; tr < 2; ++tr) {
    int n = w * 32 + tr * 16 + r;
    re[tr] = *reinterpret_cast<const int2*>(&nb[((size_t)b * 128 + n) * 2]);
  }
#pragma unroll
  for (int tr = 0; tr < 2; ++tr) {
    int n = w * 32 + tr * 16 + r;
    const float* iptr = &inp[((size_t)b * 128 + n) * 64 + c * 8];
    f32x4 iv0 = *reinterpret_cast<const f32x4*>(iptr);
    f32x4 iv1 = *reinterpret_cast<const f32x4*>(iptr + 4);
    f32x4 iv2 = *reinterpret_cast<const f32x4*>(iptr + 32);
    f32x4 iv3 = *reinterpret_cast<const f32x4*>(iptr + 36);
    const float* rptr = &mlp[(size_t)re[tr].x * 64 + c * 8];
    f32x4 rv0 = *reinterpret_cast<const f32x4*>(rptr);
    f32x4 rv1 = *reinterpret_cast<const f32x4*>(rptr + 4);
    f32x4 rv2 = *reinterpret_cast<const f32x4*>(rptr + 32);
    f32x4 rv3 = *reinterpret_cast<const f32x4*>(rptr + 36);
    float s1 = rv0[0]*rv0[0] + rv0[1]*rv0[1] + rv0[2]*rv0[2] + rv0[3]*rv0[3]
             + rv1[0]*rv1[0] + rv1[1]*rv1[1] + rv1[2]*rv1[2] + rv1[3]*rv1[3]
             + rv2[0]*rv2[0] + rv2[1]*rv2[1] + rv2[2]*rv2[2] + rv2[3]*rv2[3]
             + rv3[0]*rv3[0] + rv3[1]*rv3[1] + rv3[2]*rv3[2] + rv3[3]*rv3[3];
    float s2 = iv0[0]*rv0[0] + iv0[1]*rv0[1] + iv0[2]*rv0[2] + iv0[3]*rv0[3]
             + iv1[0]*rv1[0] + iv1[1]*rv1[1] + iv1[2]*rv1[2] + iv1[3]*rv1[3]
             + iv2[0]*rv2[0] + iv2[1]*rv2[1] + iv2[2]*rv2[2] + iv2[3]*rv2[3]
             + iv3[0]*rv3[0] + iv3[1]*rv3[1] + iv3[2]*rv3[2] + iv3[3]*rv3[3];
    // reduce across the 4 c-chunks (lanes r, r+16, r+32, r+48)
    s1 += swz_xor16(s1);  s2 += swz_xor16(s2);
    s1 += __shfl_xor(s1, 32, 64);
    s2 += __shfl_xor(s2, 32, 64);
    float f   = s2 / fmaxf(s1, 1e-24f);
    float msk = (re[tr].y >= NE) ? 0.0f : 1.0f;
    bf16x8 a0, a1;
#pragma unroll
    for (int j = 0; j < 4; ++j) {
      a0[j]     = (__bf16)((iv0[j] - f * rv0[j]) * msk);
      a0[j + 4] = (__bf16)((iv1[j] - f * rv1[j]) * msk);
      a1[j]     = (__bf16)((iv2[j] - f * rv2[j]) * msk);
      a1[j + 4] = (__bf16)((iv3[j] - f * rv3[j]) * msk);
    }
    af[tr][0] = a0;
    af[tr][1] = a1;
  }

  // ---- phase B: C = T @ W2 (+qpart) for own 32 rows; logits via tanh ----
  float p[2][4] = {{0,0,0,0},{0,0,0,0}};
#pragma unroll
  for (int h = 0; h < 2; ++h) {       // two tc-halves: halves acc VGPR pressure
    f32x4 acc[2][4];
#pragma unroll
    for (int tc2 = 0; tc2 < 4; ++tc2) {
      float qv = qpv[h * 4 + tc2];    // D layout: col = lane&15 (all 4 regs)
      acc[0][tc2] = f32x4{qv, qv, qv, qv};
      acc[1][tc2] = f32x4{qv, qv, qv, qv};
    }
#pragma unroll
    for (int tc2 = 0; tc2 < 4; ++tc2) {
      int tc = h * 4 + tc2;
      bf16x8 b0 = *reinterpret_cast<const bf16x8*>(wsf + ((tc * 2 + 0) * 64 + lane) * 8);
      bf16x8 b1 = *reinterpret_cast<const bf16x8*>(wsf + ((tc * 2 + 1) * 64 + lane) * 8);
      acc[0][tc2] = __builtin_amdgcn_mfma_f32_16x16x32_bf16(af[0][0], b0, acc[0][tc2], 0, 0, 0);
      acc[1][tc2] = __builtin_amdgcn_mfma_f32_16x16x32_bf16(af[1][0], b0, acc[1][tc2], 0, 0, 0);
      acc[0][tc2] = __builtin_amdgcn_mfma_f32_16x16x32_bf16(af[0][1], b1, acc[0][tc2], 0, 0, 0);
      acc[1][tc2] = __builtin_amdgcn_mfma_f32_16x16x32_bf16(af[1][1], b1, acc[1][tc2], 0, 0, 0);
    }
#pragma unroll
    for (int tr = 0; tr < 2; ++tr)
#pragma unroll
      for (int tc2 = 0; tc2 < 4; ++tc2) {
        float v = vv[h * 4 + tc2];
        p[tr][0] += fast_tanh(acc[tr][tc2][0]) * v;
        p[tr][1] += fast_tanh(acc[tr][tc2][1]) * v;
        p[tr][2] += fast_tanh(acc[tr][tc2][2]) * v;
        p[tr][3] += fast_tanh(acc[tr][tc2][3]) * v;
      }
  }
#pragma unroll
  for (int tr = 0; tr < 2; ++tr) {
    float p0 = red16(p[tr][0]), p1 = red16(p[tr][1]);
    float p2 = red16(p[tr][2]), p3 = red16(p[tr][3]);
    if (r == 0) {
      int row = w * 32 + tr * 16 + c * 4;  // D layout: row = (lane>>4)*4 + reg
      plog[row + 0] = p0;
      plog[row + 1] = p1;
      plog[row + 2] = p2;
      plog[row + 3] = p3;
    }
  }
  __syncthreads();   // barrier 1 of 2: plog complete (softmax needs all rows)

  // ---- softmax: every wave computes m,s redundantly; aw for own rows ----
  {
    int e0i = nb[((size_t)b * 128 + lane) * 2 + 1];
    int e1i = nb[((size_t)b * 128 + lane + 64) * 2 + 1];
    float l0 = plog[lane]      - ((e0i == NE) ? 1e19f : 0.0f);
    float l1 = plog[lane + 64] - ((e1i == NE) ? 1e19f : 0.0f);
    float m = fmaxf(l0, l1);
    m = fmaxf(m, __shfl_xor(m, 1, 64));
    m = fmaxf(m, __shfl_xor(m, 2, 64));
    m = fmaxf(m, __shfl_xor(m, 4, 64));
    m = fmaxf(m, __shfl_xor(m, 8, 64));
    m = fmaxf(m, __shfl_xor(m, 16, 64));
    m = fmaxf(m, __shfl_xor(m, 32, 64));
    float e0 = __expf(l0 - m), e1 = __expf(l1 - m);
    float s = e0 + e1;
    s += __shfl_xor(s, 1, 64);
    s += __shfl_xor(s, 2, 64);
    s += __shfl_xor(s, 4, 64);
    s += __shfl_xor(s, 8, 64);
    s += __shfl_xor(s, 16, 64);
    s += __shfl_xor(s, 32, 64);
    float rcp = __builtin_amdgcn_rcpf(s);
    float inv = rcp * (2.0f - s * rcp);            // NR-refined 1/s
    if (lane < 32) {
      int eri = nb[((size_t)b * 128 + rown) * 2 + 1];
      float lg = plog[rown] - ((eri == NE) ? 1e19f : 0.0f);
      float aw = __expf(lg - m) * inv + wr;
      awl[rown] = aw;
      float* awout = out + (size_t)NB * 64;
      awout[(size_t)b * 128 + rown] = aw;          // coalesced per-wave slice
    }
  }
  // phase C reads awl only for THIS wave's rows -> compiler's in-wave
  // lgkmcnt wait suffices, no barrier.

  // ---- phase C: own-rows partial of output[d] = sum_n T[n][d]*aw[n] ----
  {
    float po0[8] = {0,0,0,0,0,0,0,0};
    float po1[8] = {0,0,0,0,0,0,0,0};
#pragma unroll
    for (int tr = 0; tr < 2; ++tr) {
      float a = awl[w * 32 + tr * 16 + r];
      bf16x8 a0 = af[tr][0], a1 = af[tr][1];
#pragma unroll
      for (int e = 0; e < 8; ++e) {
        po0[e] += (float)a0[e] * a;
        po1[e] += (float)a1[e] * a;
      }
    }
    // reduce over rows r (16 contiguous lanes within each c-group)
#pragma unroll
    for (int e = 0; e < 8; ++e) {
      po0[e] = red16(po0[e]);
      po1[e] = red16(po1[e]);
    }
    if (r == 0) {
#pragma unroll
      for (int e = 0; e < 8; ++e) {
        part[w][c * 8 + e]      = po0[e];
        part[w][32 + c * 8 + e] = po1[e];
      }
    }
  }
  __syncthreads();   // barrier 2 of 2: part complete
  if (t < 64)
    out[(size_t)b * 64 + t] = part[0][t] + part[1][t] + part[2][t] + part[3][t];
}

// ---- host ----------------------------------------------------------------
extern "C" void kernel_launch(void* const* d_in, const int* in_sizes, int n_in,
                              void* d_out, int out_size, void* d_ws, size_t ws_size,
                              hipStream_t stream) {
  const float* inp  = (const float*)d_in[0];
  const int*   nb   = (const int*)d_in[1];
  const int*   qid  = (const int*)d_in[2];
  const float* wgt  = (const float*)d_in[3];
  const float* mlp  = (const float*)d_in[4];
  const float* qrel = (const float*)d_in[5];
  const float* attw = (const float*)d_in[6];
  const float* attv = (const float*)d_in[7];
  float* out = (float*)d_out;

  // ws layout: [0,16384) bf16 B-fragments; [16384, 16384+512000) qpart f32
  __bf16* wsf   = (__bf16*)d_ws;
  float*  qpart = (float*)((char*)d_ws + 16384);

  prep_kernel<<<1001, 128, 0, stream>>>(attw, qrel, wsf, qpart);
  attn_kernel<<<NB, 256, 0, stream>>>(inp, nb, qid, wgt, mlp, attv, wsf, qpart, out);
}